// Round 1
// baseline (186.615 us; speedup 1.0000x reference)
//
#include <hip/hip_runtime.h>
#include <stdint.h>

// BitConv1d: out = conv1d(x, sign(w), pad=1) * mean|w| * scale
// (x_scale cancels exactly: conv(x/s,w)*s == conv(x,w))
//
// Workspace layout (needs ~1.6 MB):
//   float[256]  @ byte 0     : block partial sums of |w|
//   float       @ byte 1024  : final factor = mean|w| * scale
//   ushort[786432] @ byte 2048 : sign(w) as bf16, layout [t][ci>>3][co][ci&7]

#define CIN   512
#define COUT  512
#define LLEN  4096
#define NBAT  16
#define KW    3
#define WELEMS (COUT*CIN*KW)

typedef __bf16 bf16x8 __attribute__((ext_vector_type(8)));
typedef float  f32x4  __attribute__((ext_vector_type(4)));

__device__ __forceinline__ uint32_t f2bf(float f) {
    union { float f; uint32_t u; } v; v.f = f;
    return (v.u + 0x7fffu + ((v.u >> 16) & 1u)) >> 16;   // RNE
}

// ---------------- w_scale reduction (deterministic, 2-stage) ----------------
__global__ __launch_bounds__(256) void wabs_partial(const float* __restrict__ w,
                                                    float* __restrict__ partial) {
    __shared__ float red[256];
    int tid = threadIdx.x;
    float s = 0.f;
    for (int i = blockIdx.x * 256 + tid; i < WELEMS; i += 256 * 256)
        s += fabsf(w[i]);
    red[tid] = s;
    __syncthreads();
    for (int off = 128; off > 0; off >>= 1) {
        if (tid < off) red[tid] += red[tid + off];
        __syncthreads();
    }
    if (tid == 0) partial[blockIdx.x] = red[0];
}

__global__ __launch_bounds__(256) void wscale_final(const float* __restrict__ partial,
                                                    const float* __restrict__ scale,
                                                    float* __restrict__ fac) {
    __shared__ float red[256];
    int tid = threadIdx.x;
    red[tid] = partial[tid];
    __syncthreads();
    for (int off = 128; off > 0; off >>= 1) {
        if (tid < off) red[tid] += red[tid + off];
        __syncthreads();
    }
    if (tid == 0) fac[0] = red[0] * (1.0f / (float)WELEMS) * scale[0];
}

// ---------------- pack sign(w) -> bf16 in MFMA-friendly order ----------------
// dst element index: ((t*64 + (ci>>3))*512 + co)*8 + (ci&7)
__global__ __launch_bounds__(256) void pack_w(const float* __restrict__ w,
                                              unsigned short* __restrict__ wsw) {
    int idx = blockIdx.x * 256 + threadIdx.x;      // co*512 + ci
    if (idx >= COUT * CIN) return;
    int co = idx >> 9, ci = idx & 511;
#pragma unroll
    for (int t = 0; t < KW; ++t) {
        float v = w[idx * 3 + t];
        unsigned short b = (v > 0.f) ? 0x3F80 : ((v < 0.f) ? 0xBF80 : 0);
        wsw[((t * 64 + (ci >> 3)) * 512 + co) * 8 + (ci & 7)] = b;
    }
}

// ---------------- conv as MFMA GEMM ----------------
// Block tile: 128 (co) x 128 (l), 4 waves in 2x2, acc 4x4 16x16 subtiles/wave.
// K-loop: ci chunks of 32; per chunk 3 taps (shifted x columns).
// A (weights) LDS: [t][ks][co128][j8] bf16 -> linear, conflict-light b128 reads.
// B (x) LDS: [ll 0..129][kslot^((ll>>1)&3)][j8] bf16, 64B row stride;
//            swizzle makes both read (ll stride 1) and write (ll stride 4) ~2-way.
__global__ __launch_bounds__(256) void conv_mfma(const float* __restrict__ x,
                                                 const unsigned short* __restrict__ wsw,
                                                 const float* __restrict__ fac,
                                                 float* __restrict__ out) {
    int bid = blockIdx.x;
    int cob = bid & 3;            // 4 co tiles  (co fastest: share x tile in L2)
    int lb  = (bid >> 2) & 31;    // 32 l tiles
    int n   = bid >> 7;           // 16 samples
    int co0 = cob * 128;
    int l0  = lb * 128;

    __shared__ uint4 smemA[1536];   // 24576 B: [t3][ks4][co128][j8] bf16
    __shared__ uint4 smemB[520];    //  8320 B: [ll130][32] bf16, 64B rows
    char* As = (char*)smemA;
    char* Bs = (char*)smemB;

    int tid  = threadIdx.x;
    int wave = tid >> 6;
    int lane = tid & 63;
    int wco  = (wave >> 1) * 64;   // wave tile: 64 co x 64 l
    int wl   = (wave & 1) * 64;
    int m    = lane & 15;
    int ks   = lane >> 4;

    // B staging assignment: ci pair p = tid&15 (ci=2p,2p+1), f4-col = tid>>4 (+16)
    const int p  = tid & 15;
    const int fb = tid >> 4;

    f32x4 acc[4][4];
#pragma unroll
    for (int i = 0; i < 4; ++i)
#pragma unroll
        for (int j = 0; j < 4; ++j) acc[i][j] = (f32x4){0.f, 0.f, 0.f, 0.f};

    for (int c = 0; c < 16; ++c) {          // ci chunks of 32
        __syncthreads();

        // ---- stage A: 24KB linear copy from pre-packed ws ----
#pragma unroll
        for (int it = 0; it < 6; ++it) {
            int g = it * 256 + tid;          // 0..1535 uint4
            int s = g >> 7;                  // segment 0..11  (= t*4+ks)
            int r = g & 127;                 // co within tile
            int ts = s >> 2, kss = s & 3;
            smemA[g] = *reinterpret_cast<const uint4*>(
                wsw + (((ts * 64 + c * 4 + kss) * 512) + (co0 + r)) * 8);
        }

        // ---- stage B: fp32 -> bf16 convert + swizzled scatter ----
        {
            const float* xrow0 = x + ((size_t)(n * 512 + c * 32 + 2 * p)) * LLEN + l0;
            const float* xrow1 = xrow0 + LLEN;
#pragma unroll
            for (int half = 0; half < 2; ++half) {
                int f = fb + half * 16;                       // float4 column 0..31
                float4 a = reinterpret_cast<const float4*>(xrow0)[f];
                float4 b = reinterpret_cast<const float4*>(xrow1)[f];
#pragma unroll
                for (int e = 0; e < 4; ++e) {
                    int ll = f * 4 + 1 + e;                   // 1..128
                    float av = ((const float*)&a)[e];
                    float bv = ((const float*)&b)[e];
                    uint32_t pk = f2bf(av) | (f2bf(bv) << 16);
                    int kslot = p >> 2;                       // (2p)>>3
                    int jj = (2 * p) & 7;
                    int byteoff = ll * 64 + ((kslot ^ ((ll >> 1) & 3)) << 4) + jj * 2;
                    *reinterpret_cast<uint32_t*>(Bs + byteoff) = pk;
                }
            }
            // halo columns ll=0 (l0-1) and ll=129 (l0+128)
            if (tid < 32) {
                int ci = tid;
                float v = (l0 > 0)
                    ? x[((size_t)(n * 512 + c * 32 + ci)) * LLEN + l0 - 1] : 0.f;
                int byteoff = 0 * 64 + (((ci >> 3) ^ 0) << 4) + (ci & 7) * 2;
                *reinterpret_cast<unsigned short*>(Bs + byteoff) = (unsigned short)f2bf(v);
            } else if (tid < 64) {
                int ci = tid - 32;
                float v = (l0 + 128 < LLEN)
                    ? x[((size_t)(n * 512 + c * 32 + ci)) * LLEN + l0 + 128] : 0.f;
                int ll = 129;
                int byteoff = ll * 64 + (((ci >> 3) ^ ((ll >> 1) & 3)) << 4) + (ci & 7) * 2;
                *reinterpret_cast<unsigned short*>(Bs + byteoff) = (unsigned short)f2bf(v);
            }
        }
        __syncthreads();

        // ---- compute: 3 taps x 4x4 MFMA ----
#pragma unroll
        for (int t = 0; t < KW; ++t) {
            bf16x8 afr[4], bfr[4];
#pragma unroll
            for (int ms = 0; ms < 4; ++ms) {
                int co = wco + ms * 16 + m;
                afr[ms] = *reinterpret_cast<const bf16x8*>(
                    As + ((t * 4 + ks) * 128 + co) * 16);
            }
#pragma unroll
            for (int ns = 0; ns < 4; ++ns) {
                int ll = wl + ns * 16 + m + t;                // shift by tap
                bfr[ns] = *reinterpret_cast<const bf16x8*>(
                    Bs + ll * 64 + ((ks ^ ((ll >> 1) & 3)) << 4));
            }
#pragma unroll
            for (int ms = 0; ms < 4; ++ms)
#pragma unroll
                for (int ns = 0; ns < 4; ++ns)
                    acc[ms][ns] = __builtin_amdgcn_mfma_f32_16x16x32_bf16(
                        afr[ms], bfr[ns], acc[ms][ns], 0, 0, 0);
        }
    }

    // ---- epilogue: D lane map col=lane&15, row=(lane>>4)*4+r ----
    float fscale = fac[0];
    int r4 = (lane >> 4) * 4;
#pragma unroll
    for (int ms = 0; ms < 4; ++ms) {
#pragma unroll
        for (int ns = 0; ns < 4; ++ns) {
            int col  = l0 + wl + ns * 16 + m;
            int row0 = co0 + wco + ms * 16 + r4;
            float* o = out + ((size_t)(n * 512 + row0)) * LLEN + col;
#pragma unroll
            for (int r = 0; r < 4; ++r)
                o[(size_t)r * LLEN] = acc[ms][ns][r] * fscale;
        }
    }
}

extern "C" void kernel_launch(void* const* d_in, const int* in_sizes, int n_in,
                              void* d_out, int out_size, void* d_ws, size_t ws_size,
                              hipStream_t stream) {
    const float* x     = (const float*)d_in[0];
    const float* w     = (const float*)d_in[1];
    const float* scale = (const float*)d_in[2];
    float* out = (float*)d_out;

    float* partials = (float*)d_ws;                          // 256 floats
    float* fac      = (float*)((char*)d_ws + 1024);          // 1 float
    unsigned short* wsw = (unsigned short*)((char*)d_ws + 2048);  // 786432 bf16

    wabs_partial<<<256, 256, 0, stream>>>(w, partials);
    wscale_final<<<1, 256, 0, stream>>>(partials, scale, fac);
    pack_w<<<(COUT * CIN + 255) / 256, 256, 0, stream>>>(w, wsw);
    conv_mfma<<<NBAT * 4 * 32, 256, 0, stream>>>(x, wsw, fac, out);
}